// Round 15
// baseline (50.669 us; speedup 1.0000x reference)
//
#include <hip/hip_runtime.h>

#define NB 16
#define NC 7
#define NK 6
#define HC 160
#define WC 160
#define HF 640
#define WF 640
#define NCOARSE (HC*WC)             // 25600 coarse pixels per batch
#define NFINE   (HF*WF)             // 409600 fine pixels per batch
#define NQ4 (NCOARSE/4)             // 6400 float4/uint4 per batch
#define ITER 2
#define CHUNKS_PER_B 50
#define KBLOCKS (NB*CHUNKS_PER_B)   // 800
#define NACC 28                     // 27 + threshold-indep d-term
#define EPSF 1e-6f

// ---------------- ws layout (bytes) ----------------
// pf       float[800*32]   @ 0        (102400)  [fully written by K1]
// pi       int[800*2]      @ 102400   (6400)    [fully written by K1]
// metrics  float[16*8]     @ 108800   (512)     [fully written by BD]
// counter  int             @ 109312   (16)      [reset by K1 block 0]
// bits     uint[409600]    @ 109328   (1638400) [fully written by K1]
#define WS_PI    102400
#define WS_MET   108800
#define WS_CTR   109312
#define WS_BITS  109328

__device__ __forceinline__ unsigned score_key(float s) {
    unsigned u = __float_as_uint(s);
    return (u & 0x80000000u) ? ~u : (u | 0x80000000u);
}

typedef float vfloat4 __attribute__((ext_vector_type(4)));

__device__ __forceinline__ float4 ntload4(const float* p) {
    vfloat4 v = __builtin_nontemporal_load(reinterpret_cast<const vfloat4*>(p));
    return float4{v.x, v.y, v.z, v.w};
}

// ---------- K1: fused bit-pack + main reduction (threshold-independent), R12 body + nt loads ----------
__global__ __launch_bounds__(256) void psel_K1(
    const float* __restrict__ maps, const float* __restrict__ gt,
    const float* __restrict__ gk, const float* __restrict__ tm,
    unsigned* __restrict__ bitsbuf, float* __restrict__ pf, int* __restrict__ pi,
    int* __restrict__ counter)
{
    int t = threadIdx.x;
    int bid = blockIdx.x;
    if (bid == 0 && t == 0) *counter = 0;   // reset finisher counter each call
    int b = bid / CHUNKS_PER_B;
    int c0 = (bid % CHUNKS_PER_B) * ITER;

    float acc[NACC];
    #pragma unroll
    for (int i = 0; i < NACC; ++i) acc[i] = 0.f;
    int posA = 0, negA = 0;

    const float* gtb = gt + (size_t)b * NFINE;
    const float* tmb = tm + (size_t)b * NFINE;

    #pragma unroll
    for (int it = 0; it < ITER; ++it) {
        int r = (c0 + it) * 256 + t;
        int cy = r / WC, cx = r % WC;

        // ---- issue ALL loads for this pixel up front (ILP), non-temporal ----
        float4 g4[4], m4[4];
        #pragma unroll
        for (int row = 0; row < 4; ++row) {
            int off = (cy*4 + row)*WF + cx*4;
            g4[row] = ntload4(gtb + off);
            m4[row] = ntload4(tmb + off);
        }
        float mv[NC];
        #pragma unroll
        for (int c = 0; c < NC; ++c)
            mv[c] = __builtin_nontemporal_load(maps + ((size_t)(b*NC + c))*NCOARSE + r);
        float4 k4[NK][4];
        #pragma unroll
        for (int k = 0; k < NK; ++k) {
            const float* gkb = gk + (size_t)(b*NK + k) * NFINE + (cy*4)*WF + cx*4;
            #pragma unroll
            for (int row = 0; row < 4; ++row)
                k4[k][row] = ntload4(gkb + row*WF);
        }

        // ---- bits ----
        unsigned gb = 0, mb = 0;
        #pragma unroll
        for (int row = 0; row < 4; ++row) {
            unsigned sh = 4*row;
            gb |= ((g4[row].x > 0.5f) ? 1u : 0u) << (sh+0);
            gb |= ((g4[row].y > 0.5f) ? 1u : 0u) << (sh+1);
            gb |= ((g4[row].z > 0.5f) ? 1u : 0u) << (sh+2);
            gb |= ((g4[row].w > 0.5f) ? 1u : 0u) << (sh+3);
            mb |= ((m4[row].x > 0.5f) ? 1u : 0u) << (sh+0);
            mb |= ((m4[row].y > 0.5f) ? 1u : 0u) << (sh+1);
            mb |= ((m4[row].z > 0.5f) ? 1u : 0u) << (sh+2);
            mb |= ((m4[row].w > 0.5f) ? 1u : 0u) << (sh+3);
        }
        __builtin_nontemporal_store((mb << 16) | gb, bitsbuf + b*NCOARSE + r);
        unsigned gmb = gb & mb;
        posA += __popc(gmb);
        negA += 16 - __popc(gb);
        float cm  = (float)__popc(mb);
        float cgm = (float)__popc(gmb);

        // ---- sigmoids ----
        float sig[NC];
        #pragma unroll
        for (int c = 0; c < NC; ++c) sig[c] = 1.0f / (1.0f + expf(-mv[c]));
        bool at = mv[0] > 0.0f;
        bool a5 = mv[6] > 0.0f;

        // ---- gk masked sums ----
        float cgkm[NK];
        float cg5mg = 0.f;
        #pragma unroll
        for (int k = 0; k < NK; ++k) {
            float s = 0.f;
            #pragma unroll
            for (int row = 0; row < 4; ++row) {
                unsigned mrow = (mb >> (4*row)) & 15u;
                if (mrow & 1u) s += k4[k][row].x;
                if (mrow & 2u) s += k4[k][row].y;
                if (mrow & 4u) s += k4[k][row].z;
                if (mrow & 8u) s += k4[k][row].w;
            }
            cgkm[k] = s;
        }
        #pragma unroll
        for (int row = 0; row < 4; ++row) {
            unsigned grow = (gmb >> (4*row)) & 15u;
            if (grow & 1u) cg5mg += k4[NK-1][row].x;
            if (grow & 2u) cg5mg += k4[NK-1][row].y;
            if (grow & 4u) cg5mg += k4[NK-1][row].z;
            if (grow & 8u) cg5mg += k4[NK-1][row].w;
        }

        // ---- accumulate the 28 sums ----
        float s0 = sig[0];
        acc[0] += s0 * cgm;
        acc[1] += s0 * s0 * cgm;
        acc[2] += cgm;
        acc[3] += cm;
        if (at) {
            acc[4] += cgm;
            acc[5] += cm;
            #pragma unroll
            for (int k = 0; k < NK; ++k) {
                float sk = sig[k+1];
                acc[6 + 3*k] += sk * cgkm[k];
                acc[7 + 3*k] += sk * sk * cm;
                acc[8 + 3*k] += cgkm[k];
            }
        }
        if (a5) {
            acc[24] += cg5mg;
            acc[25] += cgm;
        }
        acc[26] += cg5mg;
        acc[27] += s0 * s0 * (cm - cgm);   // threshold-indep d-term
    }

    // ---- block reduce 28 floats + 2 ints, plain store (no atomics) ----
    #pragma unroll
    for (int i = 0; i < NACC; ++i) {
        #pragma unroll
        for (int off = 32; off; off >>= 1)
            acc[i] += __shfl_down(acc[i], off);
    }
    #pragma unroll
    for (int off = 32; off; off >>= 1) {
        posA += __shfl_down(posA, off);
        negA += __shfl_down(negA, off);
    }
    __shared__ float red[4][NACC];
    __shared__ int sp[4], sn[4];
    int wid = t >> 6, lane = t & 63;
    if (lane == 0) {
        #pragma unroll
        for (int i = 0; i < NACC; ++i) red[wid][i] = acc[i];
        sp[wid] = posA; sn[wid] = negA;
    }
    __syncthreads();
    if (t < NACC)
        pf[bid*32 + t] = red[0][t] + red[1][t] + red[2][t] + red[3][t];
    if (t == 0) {
        pi[2*bid]   = sp[0]+sp[1]+sp[2]+sp[3];
        pi[2*bid+1] = sn[0]+sn[1]+sn[2]+sn[3];
    }
}

// Block-wide (1024 thr) weighted descending select over LDS histogram.
// (general path only — never taken for the benchmark distribution)
template<int NBINS>
__device__ __forceinline__ int bsel(int* __restrict__ lh, int* __restrict__ ws16,
                                    int* __restrict__ wsuf, int* __restrict__ res,
                                    int k, int& krem)
{
    constexpr int CH = NBINS / 1024;
    int t = threadIdx.x, wid = t >> 6, lane = t & 63;
    __syncthreads();
    int c = 0;
    #pragma unroll
    for (int j = 0; j < CH; ++j) c += lh[t*CH + j];
    int s = c;
    #pragma unroll
    for (int off = 1; off < 64; off <<= 1) {
        int v = __shfl_down(s, off);
        if (lane + off < 64) s += v;
    }
    if (lane == 0) ws16[wid] = s;
    __syncthreads();
    if (t < 16) {
        int sum = 0;
        for (int j = t; j < 16; ++j) sum += ws16[j];
        wsuf[t] = sum;
    }
    if (t == 0) { wsuf[16] = 0; res[0] = 0; res[1] = k; }
    __syncthreads();
    int G = s + wsuf[wid + 1];
    int above = G - c;
    if (G >= k && above < k) {
        int cum = above;
        for (int u = t*CH + CH - 1; u >= t*CH; --u) {
            cum += lh[u];
            if (cum >= k) { res[0] = u; res[1] = k - (cum - lh[u]); break; }
        }
    }
    __syncthreads();
    int bin = res[0]; krem = res[1];
    __syncthreads();
    return bin;
}

// ---------- BD: threshold + per-batch finalize + last-block output sum ----------
__global__ __launch_bounds__(1024) void psel_BD(
    const float* __restrict__ maps, const unsigned* __restrict__ bitsbuf,
    const float* __restrict__ pf, const int* __restrict__ pi,
    float* __restrict__ metrics, int* __restrict__ counter,
    float* __restrict__ out)
{
    __shared__ float fin[NACC];
    __shared__ int ipn[2];
    __shared__ float thrT_sh;
    int b = blockIdx.x, t = threadIdx.x;
    int wid = t >> 6, lane = t & 63;

    // ---- wave-0 reduce of pf/pi (50 rows per batch) ----
    if (t < 64) {
        float loc[NACC];
        #pragma unroll
        for (int j = 0; j < NACC; ++j) loc[j] = 0.f;
        int p = 0, n = 0;
        if (t < CHUNKS_PER_B) {
            const float* row = pf + (size_t)(b*CHUNKS_PER_B + t) * 32;
            #pragma unroll
            for (int j = 0; j < NACC; ++j) loc[j] = row[j];
            p = pi[(b*CHUNKS_PER_B + t)*2];
            n = pi[(b*CHUNKS_PER_B + t)*2 + 1];
        }
        #pragma unroll
        for (int j = 0; j < NACC; ++j) {
            #pragma unroll
            for (int off = 32; off; off >>= 1)
                loc[j] += __shfl_down(loc[j], off);
        }
        #pragma unroll
        for (int off = 32; off; off >>= 1) {
            p += __shfl_down(p, off);
            n += __shfl_down(n, off);
        }
        if (t == 0) {
            #pragma unroll
            for (int j = 0; j < NACC; ++j) fin[j] = loc[j];
            ipn[0] = p; ipn[1] = n;
        }
    }
    __syncthreads();
    int pos = ipn[0], negT = ipn[1];
    long long nn = (long long)pos * 3; if (nn > negT) nn = negT;
    int k = (int)nn;

    if (pos == 0 || k == 0 || k == negT) {
        // trivial: every pixel selected (or fallback sel=m) -> d-term already in fin[27]
        if (t == 0) thrT_sh = fin[27];
    } else {
        // ---- general weighted radix select + masked d-term re-scan ----
        __shared__ unsigned wpack[NQ4];
        __shared__ int lh[2048];
        __shared__ int ws16[16], wsuf[17], res[2];
        __shared__ float s16[16];
        const float4* mp4 = reinterpret_cast<const float4*>(maps + (size_t)b * NC * NCOARSE);
        const uint4*  bb4 = reinterpret_cast<const uint4*>(bitsbuf + (size_t)b * NCOARSE);

        for (int j = t; j < 2048; j += 1024) lh[j] = 0;
        __syncthreads();
        for (int i4 = t; i4 < NQ4; i4 += 1024) {
            float4 m4 = mp4[i4];
            uint4  b4 = bb4[i4];
            float    mvx[4] = {m4.x, m4.y, m4.z, m4.w};
            unsigned bv[4] = {b4.x, b4.y, b4.z, b4.w};
            unsigned pk = 0;
            #pragma unroll
            for (int j = 0; j < 4; ++j) {
                int w = 16 - __popc(bv[j] & 0xFFFFu);
                pk |= (unsigned)w << (8*j);
                if (w) atomicAdd(&lh[score_key(mvx[j]) >> 21], w);
            }
            wpack[i4] = pk;
        }
        int v = bsel<2048>(lh, ws16, wsuf, res, k, k);
        unsigned prefix = (unsigned)v;

        for (int j = t; j < 2048; j += 1024) lh[j] = 0;
        __syncthreads();
        for (int i4 = t; i4 < NQ4; i4 += 1024) {
            float4 m4 = mp4[i4];
            unsigned pk = wpack[i4];
            float mvx[4] = {m4.x, m4.y, m4.z, m4.w};
            #pragma unroll
            for (int j = 0; j < 4; ++j) {
                int w = (pk >> (8*j)) & 255;
                if (w) {
                    unsigned key = score_key(mvx[j]);
                    if ((key >> 21) == prefix) atomicAdd(&lh[(key >> 10) & 2047u], w);
                }
            }
        }
        v = bsel<2048>(lh, ws16, wsuf, res, k, k);
        prefix = (prefix << 11) | (unsigned)v;

        for (int j = t; j < 1024; j += 1024) lh[j] = 0;
        __syncthreads();
        for (int i4 = t; i4 < NQ4; i4 += 1024) {
            float4 m4 = mp4[i4];
            unsigned pk = wpack[i4];
            float mvx[4] = {m4.x, m4.y, m4.z, m4.w};
            #pragma unroll
            for (int j = 0; j < 4; ++j) {
                int w = (pk >> (8*j)) & 255;
                if (w) {
                    unsigned key = score_key(mvx[j]);
                    if ((key >> 10) == prefix) atomicAdd(&lh[key & 1023u], w);
                }
            }
        }
        v = bsel<1024>(lh, ws16, wsuf, res, k, k);
        unsigned thrkey = (prefix << 10) | (unsigned)v;

        float ssum = 0.f;
        for (int i4 = t; i4 < NQ4; i4 += 1024) {
            float4 m4 = mp4[i4];
            uint4  b4 = bb4[i4];
            float    mvx[4] = {m4.x, m4.y, m4.z, m4.w};
            unsigned bv[4] = {b4.x, b4.y, b4.z, b4.w};
            #pragma unroll
            for (int j = 0; j < 4; ++j) {
                unsigned w = bv[j];
                float d = (float)(__popc(w >> 16) - __popc(w & (w >> 16) & 0xFFFFu));
                if (d > 0.f && score_key(mvx[j]) >= thrkey) {
                    float s = 1.0f / (1.0f + expf(-mvx[j]));
                    ssum += s * s * d;
                }
            }
        }
        #pragma unroll
        for (int off = 32; off; off >>= 1) ssum += __shfl_down(ssum, off);
        if (lane == 0) s16[wid] = ssum;
        __syncthreads();
        if (t == 0) {
            float tt = 0.f;
            for (int j = 0; j < 16; ++j) tt += s16[j];
            thrT_sh = tt;
        }
    }
    __syncthreads();

    // ---- per-batch algebra + last-finisher output sum ----
    if (t == 0) {
        const float* a = fin;
        float At = a[0], Bt = a[1] + thrT_sh, Ct = a[2], Sm = a[3], Satgm = a[4], Satm = a[5];
        float lt = 1.f - 2.f*At / (Bt + Ct + 2.f*EPSF);
        float n11 = Satgm;
        float u1 = Satm + Ct - Satgm;
        float i0 = Sm - u1;
        float u0 = Sm - n11;
        float itx = 0.5f * (i0/(u0 + EPSF) + n11/(u1 + EPSF));
        float lks = 0.f;
        #pragma unroll
        for (int kk = 0; kk < NK; ++kk) {
            float Ak = a[6+3*kk], Bk = a[7+3*kk], Ck = a[8+3*kk];
            lks += 1.f - 2.f*Ak / (Bk + Ck + 2.f*EPSF);
        }
        float lk = lks / (float)NK;
        float m11 = a[24], Sa5gm = a[25], Sg5 = a[26];
        float ku1 = Sa5gm + Sg5 - m11;
        float ki0 = Ct - ku1;
        float ku0 = Ct - m11;
        float ik = 0.5f * (ki0/(ku0 + EPSF) + m11/(ku1 + EPSF));
        float l = 0.7f*lt + 0.3f*lk;
        metrics[b*8 + 0] = l;
        metrics[b*8 + 1] = lt;
        metrics[b*8 + 2] = lk;
        metrics[b*8 + 3] = itx;
        metrics[b*8 + 4] = ik;
        __threadfence();
        int old = atomicAdd(counter, 1);
        if (old == NB - 1) {
            float v5[5] = {0.f, 0.f, 0.f, 0.f, 0.f};
            for (int bb = 0; bb < NB; ++bb) {
                #pragma unroll
                for (int j = 0; j < 5; ++j) v5[j] += metrics[bb*8 + j];
            }
            #pragma unroll
            for (int j = 0; j < 5; ++j) out[j] = v5[j];
        }
    }
}

extern "C" void kernel_launch(void* const* d_in, const int* in_sizes, int n_in,
                              void* d_out, int out_size, void* d_ws, size_t ws_size,
                              hipStream_t stream) {
    const float* maps = (const float*)d_in[0];
    const float* gt   = (const float*)d_in[1];
    const float* gk   = (const float*)d_in[2];
    const float* tm   = (const float*)d_in[3];
    float* out = (float*)d_out;
    char* ws = (char*)d_ws;
    float*    pf      = (float*)ws;
    int*      pi      = (int*)(ws + WS_PI);
    float*    metrics = (float*)(ws + WS_MET);
    int*      counter = (int*)(ws + WS_CTR);
    unsigned* bits    = (unsigned*)(ws + WS_BITS);

    psel_K1<<<KBLOCKS, 256, 0, stream>>>(maps, gt, gk, tm, bits, pf, pi, counter);
    psel_BD<<<NB, 1024, 0, stream>>>(maps, bits, pf, pi, metrics, counter, out);
}

// Round 16
// 45.525 us; speedup vs baseline: 1.1130x; 1.1130x over previous
//
#include <hip/hip_runtime.h>

#define NB 16
#define NC 7
#define NK 6
#define HC 160
#define WC 160
#define HF 640
#define WF 640
#define NCOARSE (HC*WC)             // 25600 coarse pixels per batch
#define NFINE   (HF*WF)             // 409600 fine pixels per batch
#define NQ4 (NCOARSE/4)             // 6400 float4/uint4 per batch
#define ITER 2
#define CHUNKS_PER_B 50
#define KBLOCKS (NB*CHUNKS_PER_B)   // 800
#define NACC 28                     // 27 + threshold-indep d-term
#define EPSF 1e-6f

// ---------------- ws layout (bytes) ----------------
// pf       float[800*32]   @ 0        (102400)  [fully written by K1]
// pi       int[800*2]      @ 102400   (6400)    [fully written by K1]
// metrics  float[16*8]     @ 108800   (512)     [fully written by BD]
// counter  int             @ 109312   (16)      [reset by K1 block 0]
// bits     uint[409600]    @ 109328   (1638400) [fully written by K1]
#define WS_PI    102400
#define WS_MET   108800
#define WS_CTR   109312
#define WS_BITS  109328

__device__ __forceinline__ unsigned score_key(float s) {
    unsigned u = __float_as_uint(s);
    return (u & 0x80000000u) ? ~u : (u | 0x80000000u);
}

// ---------- K1: fused bit-pack + main reduction (threshold-independent), R9/R12 body ----------
__global__ __launch_bounds__(256) void psel_K1(
    const float* __restrict__ maps, const float* __restrict__ gt,
    const float* __restrict__ gk, const float* __restrict__ tm,
    unsigned* __restrict__ bitsbuf, float* __restrict__ pf, int* __restrict__ pi,
    int* __restrict__ counter)
{
    int t = threadIdx.x;
    int bid = blockIdx.x;
    if (bid == 0 && t == 0) *counter = 0;   // reset finisher counter each call
    int b = bid / CHUNKS_PER_B;
    int c0 = (bid % CHUNKS_PER_B) * ITER;

    float acc[NACC];
    #pragma unroll
    for (int i = 0; i < NACC; ++i) acc[i] = 0.f;
    int posA = 0, negA = 0;

    const float* gtb = gt + (size_t)b * NFINE;
    const float* tmb = tm + (size_t)b * NFINE;

    #pragma unroll
    for (int it = 0; it < ITER; ++it) {
        int r = (c0 + it) * 256 + t;
        int cy = r / WC, cx = r % WC;

        // ---- issue ALL loads for this pixel up front (ILP) ----
        float4 g4[4], m4[4];
        #pragma unroll
        for (int row = 0; row < 4; ++row) {
            int off = (cy*4 + row)*WF + cx*4;
            g4[row] = *reinterpret_cast<const float4*>(gtb + off);
            m4[row] = *reinterpret_cast<const float4*>(tmb + off);
        }
        float mv[NC];
        #pragma unroll
        for (int c = 0; c < NC; ++c)
            mv[c] = maps[((size_t)(b*NC + c))*NCOARSE + r];
        float4 k4[NK][4];
        #pragma unroll
        for (int k = 0; k < NK; ++k) {
            const float* gkb = gk + (size_t)(b*NK + k) * NFINE + (cy*4)*WF + cx*4;
            #pragma unroll
            for (int row = 0; row < 4; ++row)
                k4[k][row] = *reinterpret_cast<const float4*>(gkb + row*WF);
        }

        // ---- bits ----
        unsigned gb = 0, mb = 0;
        #pragma unroll
        for (int row = 0; row < 4; ++row) {
            unsigned sh = 4*row;
            gb |= ((g4[row].x > 0.5f) ? 1u : 0u) << (sh+0);
            gb |= ((g4[row].y > 0.5f) ? 1u : 0u) << (sh+1);
            gb |= ((g4[row].z > 0.5f) ? 1u : 0u) << (sh+2);
            gb |= ((g4[row].w > 0.5f) ? 1u : 0u) << (sh+3);
            mb |= ((m4[row].x > 0.5f) ? 1u : 0u) << (sh+0);
            mb |= ((m4[row].y > 0.5f) ? 1u : 0u) << (sh+1);
            mb |= ((m4[row].z > 0.5f) ? 1u : 0u) << (sh+2);
            mb |= ((m4[row].w > 0.5f) ? 1u : 0u) << (sh+3);
        }
        bitsbuf[b*NCOARSE + r] = (mb << 16) | gb;
        unsigned gmb = gb & mb;
        posA += __popc(gmb);
        negA += 16 - __popc(gb);
        float cm  = (float)__popc(mb);
        float cgm = (float)__popc(gmb);

        // ---- sigmoids ----
        float sig[NC];
        #pragma unroll
        for (int c = 0; c < NC; ++c) sig[c] = 1.0f / (1.0f + expf(-mv[c]));
        bool at = mv[0] > 0.0f;
        bool a5 = mv[6] > 0.0f;

        // ---- gk masked sums ----
        float cgkm[NK];
        float cg5mg = 0.f;
        #pragma unroll
        for (int k = 0; k < NK; ++k) {
            float s = 0.f;
            #pragma unroll
            for (int row = 0; row < 4; ++row) {
                unsigned mrow = (mb >> (4*row)) & 15u;
                if (mrow & 1u) s += k4[k][row].x;
                if (mrow & 2u) s += k4[k][row].y;
                if (mrow & 4u) s += k4[k][row].z;
                if (mrow & 8u) s += k4[k][row].w;
            }
            cgkm[k] = s;
        }
        #pragma unroll
        for (int row = 0; row < 4; ++row) {
            unsigned grow = (gmb >> (4*row)) & 15u;
            if (grow & 1u) cg5mg += k4[NK-1][row].x;
            if (grow & 2u) cg5mg += k4[NK-1][row].y;
            if (grow & 4u) cg5mg += k4[NK-1][row].z;
            if (grow & 8u) cg5mg += k4[NK-1][row].w;
        }

        // ---- accumulate the 28 sums ----
        float s0 = sig[0];
        acc[0] += s0 * cgm;
        acc[1] += s0 * s0 * cgm;
        acc[2] += cgm;
        acc[3] += cm;
        if (at) {
            acc[4] += cgm;
            acc[5] += cm;
            #pragma unroll
            for (int k = 0; k < NK; ++k) {
                float sk = sig[k+1];
                acc[6 + 3*k] += sk * cgkm[k];
                acc[7 + 3*k] += sk * sk * cm;
                acc[8 + 3*k] += cgkm[k];
            }
        }
        if (a5) {
            acc[24] += cg5mg;
            acc[25] += cgm;
        }
        acc[26] += cg5mg;
        acc[27] += s0 * s0 * (cm - cgm);   // threshold-indep d-term
    }

    // ---- block reduce 28 floats + 2 ints, plain store (no atomics) ----
    #pragma unroll
    for (int i = 0; i < NACC; ++i) {
        #pragma unroll
        for (int off = 32; off; off >>= 1)
            acc[i] += __shfl_down(acc[i], off);
    }
    #pragma unroll
    for (int off = 32; off; off >>= 1) {
        posA += __shfl_down(posA, off);
        negA += __shfl_down(negA, off);
    }
    __shared__ float red[4][NACC];
    __shared__ int sp[4], sn[4];
    int wid = t >> 6, lane = t & 63;
    if (lane == 0) {
        #pragma unroll
        for (int i = 0; i < NACC; ++i) red[wid][i] = acc[i];
        sp[wid] = posA; sn[wid] = negA;
    }
    __syncthreads();
    if (t < NACC)
        pf[bid*32 + t] = red[0][t] + red[1][t] + red[2][t] + red[3][t];
    if (t == 0) {
        pi[2*bid]   = sp[0]+sp[1]+sp[2]+sp[3];
        pi[2*bid+1] = sn[0]+sn[1]+sn[2]+sn[3];
    }
}

// Block-wide (1024 thr) weighted descending select over LDS histogram.
// (general path only — never taken for the benchmark distribution)
template<int NBINS>
__device__ __forceinline__ int bsel(int* __restrict__ lh, int* __restrict__ ws16,
                                    int* __restrict__ wsuf, int* __restrict__ res,
                                    int k, int& krem)
{
    constexpr int CH = NBINS / 1024;
    int t = threadIdx.x, wid = t >> 6, lane = t & 63;
    __syncthreads();
    int c = 0;
    #pragma unroll
    for (int j = 0; j < CH; ++j) c += lh[t*CH + j];
    int s = c;
    #pragma unroll
    for (int off = 1; off < 64; off <<= 1) {
        int v = __shfl_down(s, off);
        if (lane + off < 64) s += v;
    }
    if (lane == 0) ws16[wid] = s;
    __syncthreads();
    if (t < 16) {
        int sum = 0;
        for (int j = t; j < 16; ++j) sum += ws16[j];
        wsuf[t] = sum;
    }
    if (t == 0) { wsuf[16] = 0; res[0] = 0; res[1] = k; }
    __syncthreads();
    int G = s + wsuf[wid + 1];
    int above = G - c;
    if (G >= k && above < k) {
        int cum = above;
        for (int u = t*CH + CH - 1; u >= t*CH; --u) {
            cum += lh[u];
            if (cum >= k) { res[0] = u; res[1] = k - (cum - lh[u]); break; }
        }
    }
    __syncthreads();
    int bin = res[0]; krem = res[1];
    __syncthreads();
    return bin;
}

// ---------- BD: threshold + per-batch finalize + last-block output sum ----------
__global__ __launch_bounds__(1024) void psel_BD(
    const float* __restrict__ maps, const unsigned* __restrict__ bitsbuf,
    const float* __restrict__ pf, const int* __restrict__ pi,
    float* __restrict__ metrics, int* __restrict__ counter,
    float* __restrict__ out)
{
    __shared__ float fin[NACC];
    __shared__ int ipn[2];
    __shared__ float thrT_sh;
    int b = blockIdx.x, t = threadIdx.x;
    int wid = t >> 6, lane = t & 63;

    // ---- wave-0 reduce of pf/pi (50 rows per batch) ----
    if (t < 64) {
        float loc[NACC];
        #pragma unroll
        for (int j = 0; j < NACC; ++j) loc[j] = 0.f;
        int p = 0, n = 0;
        if (t < CHUNKS_PER_B) {
            const float* row = pf + (size_t)(b*CHUNKS_PER_B + t) * 32;
            #pragma unroll
            for (int j = 0; j < NACC; ++j) loc[j] = row[j];
            p = pi[(b*CHUNKS_PER_B + t)*2];
            n = pi[(b*CHUNKS_PER_B + t)*2 + 1];
        }
        #pragma unroll
        for (int j = 0; j < NACC; ++j) {
            #pragma unroll
            for (int off = 32; off; off >>= 1)
                loc[j] += __shfl_down(loc[j], off);
        }
        #pragma unroll
        for (int off = 32; off; off >>= 1) {
            p += __shfl_down(p, off);
            n += __shfl_down(n, off);
        }
        if (t == 0) {
            #pragma unroll
            for (int j = 0; j < NACC; ++j) fin[j] = loc[j];
            ipn[0] = p; ipn[1] = n;
        }
    }
    __syncthreads();
    int pos = ipn[0], negT = ipn[1];
    long long nn = (long long)pos * 3; if (nn > negT) nn = negT;
    int k = (int)nn;

    if (pos == 0 || k == 0 || k == negT) {
        // trivial: every pixel selected (or fallback sel=m) -> d-term already in fin[27]
        if (t == 0) thrT_sh = fin[27];
    } else {
        // ---- general weighted radix select + masked d-term re-scan ----
        __shared__ unsigned wpack[NQ4];
        __shared__ int lh[2048];
        __shared__ int ws16[16], wsuf[17], res[2];
        __shared__ float s16[16];
        const float4* mp4 = reinterpret_cast<const float4*>(maps + (size_t)b * NC * NCOARSE);
        const uint4*  bb4 = reinterpret_cast<const uint4*>(bitsbuf + (size_t)b * NCOARSE);

        for (int j = t; j < 2048; j += 1024) lh[j] = 0;
        __syncthreads();
        for (int i4 = t; i4 < NQ4; i4 += 1024) {
            float4 m4 = mp4[i4];
            uint4  b4 = bb4[i4];
            float    mvx[4] = {m4.x, m4.y, m4.z, m4.w};
            unsigned bv[4] = {b4.x, b4.y, b4.z, b4.w};
            unsigned pk = 0;
            #pragma unroll
            for (int j = 0; j < 4; ++j) {
                int w = 16 - __popc(bv[j] & 0xFFFFu);
                pk |= (unsigned)w << (8*j);
                if (w) atomicAdd(&lh[score_key(mvx[j]) >> 21], w);
            }
            wpack[i4] = pk;
        }
        int v = bsel<2048>(lh, ws16, wsuf, res, k, k);
        unsigned prefix = (unsigned)v;

        for (int j = t; j < 2048; j += 1024) lh[j] = 0;
        __syncthreads();
        for (int i4 = t; i4 < NQ4; i4 += 1024) {
            float4 m4 = mp4[i4];
            unsigned pk = wpack[i4];
            float mvx[4] = {m4.x, m4.y, m4.z, m4.w};
            #pragma unroll
            for (int j = 0; j < 4; ++j) {
                int w = (pk >> (8*j)) & 255;
                if (w) {
                    unsigned key = score_key(mvx[j]);
                    if ((key >> 21) == prefix) atomicAdd(&lh[(key >> 10) & 2047u], w);
                }
            }
        }
        v = bsel<2048>(lh, ws16, wsuf, res, k, k);
        prefix = (prefix << 11) | (unsigned)v;

        for (int j = t; j < 1024; j += 1024) lh[j] = 0;
        __syncthreads();
        for (int i4 = t; i4 < NQ4; i4 += 1024) {
            float4 m4 = mp4[i4];
            unsigned pk = wpack[i4];
            float mvx[4] = {m4.x, m4.y, m4.z, m4.w};
            #pragma unroll
            for (int j = 0; j < 4; ++j) {
                int w = (pk >> (8*j)) & 255;
                if (w) {
                    unsigned key = score_key(mvx[j]);
                    if ((key >> 10) == prefix) atomicAdd(&lh[key & 1023u], w);
                }
            }
        }
        v = bsel<1024>(lh, ws16, wsuf, res, k, k);
        unsigned thrkey = (prefix << 10) | (unsigned)v;

        float ssum = 0.f;
        for (int i4 = t; i4 < NQ4; i4 += 1024) {
            float4 m4 = mp4[i4];
            uint4  b4 = bb4[i4];
            float    mvx[4] = {m4.x, m4.y, m4.z, m4.w};
            unsigned bv[4] = {b4.x, b4.y, b4.z, b4.w};
            #pragma unroll
            for (int j = 0; j < 4; ++j) {
                unsigned w = bv[j];
                float d = (float)(__popc(w >> 16) - __popc(w & (w >> 16) & 0xFFFFu));
                if (d > 0.f && score_key(mvx[j]) >= thrkey) {
                    float s = 1.0f / (1.0f + expf(-mvx[j]));
                    ssum += s * s * d;
                }
            }
        }
        #pragma unroll
        for (int off = 32; off; off >>= 1) ssum += __shfl_down(ssum, off);
        if (lane == 0) s16[wid] = ssum;
        __syncthreads();
        if (t == 0) {
            float tt = 0.f;
            for (int j = 0; j < 16; ++j) tt += s16[j];
            thrT_sh = tt;
        }
    }
    __syncthreads();

    // ---- per-batch algebra + last-finisher output sum ----
    if (t == 0) {
        const float* a = fin;
        float At = a[0], Bt = a[1] + thrT_sh, Ct = a[2], Sm = a[3], Satgm = a[4], Satm = a[5];
        float lt = 1.f - 2.f*At / (Bt + Ct + 2.f*EPSF);
        float n11 = Satgm;
        float u1 = Satm + Ct - Satgm;
        float i0 = Sm - u1;
        float u0 = Sm - n11;
        float itx = 0.5f * (i0/(u0 + EPSF) + n11/(u1 + EPSF));
        float lks = 0.f;
        #pragma unroll
        for (int kk = 0; kk < NK; ++kk) {
            float Ak = a[6+3*kk], Bk = a[7+3*kk], Ck = a[8+3*kk];
            lks += 1.f - 2.f*Ak / (Bk + Ck + 2.f*EPSF);
        }
        float lk = lks / (float)NK;
        float m11 = a[24], Sa5gm = a[25], Sg5 = a[26];
        float ku1 = Sa5gm + Sg5 - m11;
        float ki0 = Ct - ku1;
        float ku0 = Ct - m11;
        float ik = 0.5f * (ki0/(ku0 + EPSF) + m11/(ku1 + EPSF));
        float l = 0.7f*lt + 0.3f*lk;
        metrics[b*8 + 0] = l;
        metrics[b*8 + 1] = lt;
        metrics[b*8 + 2] = lk;
        metrics[b*8 + 3] = itx;
        metrics[b*8 + 4] = ik;
        __threadfence();
        int old = atomicAdd(counter, 1);
        if (old == NB - 1) {
            float v5[5] = {0.f, 0.f, 0.f, 0.f, 0.f};
            for (int bb = 0; bb < NB; ++bb) {
                #pragma unroll
                for (int j = 0; j < 5; ++j) v5[j] += metrics[bb*8 + j];
            }
            #pragma unroll
            for (int j = 0; j < 5; ++j) out[j] = v5[j];
        }
    }
}

extern "C" void kernel_launch(void* const* d_in, const int* in_sizes, int n_in,
                              void* d_out, int out_size, void* d_ws, size_t ws_size,
                              hipStream_t stream) {
    const float* maps = (const float*)d_in[0];
    const float* gt   = (const float*)d_in[1];
    const float* gk   = (const float*)d_in[2];
    const float* tm   = (const float*)d_in[3];
    float* out = (float*)d_out;
    char* ws = (char*)d_ws;
    float*    pf      = (float*)ws;
    int*      pi      = (int*)(ws + WS_PI);
    float*    metrics = (float*)(ws + WS_MET);
    int*      counter = (int*)(ws + WS_CTR);
    unsigned* bits    = (unsigned*)(ws + WS_BITS);

    psel_K1<<<KBLOCKS, 256, 0, stream>>>(maps, gt, gk, tm, bits, pf, pi, counter);
    psel_BD<<<NB, 1024, 0, stream>>>(maps, bits, pf, pi, metrics, counter, out);
}